// Round 16
// baseline (390.517 us; speedup 1.0000x reference)
//
#include <hip/hip_runtime.h>
#include <math.h>

#define S_DIM 512
#define R_DIM 384
#define CM 64
#define CZ 128
#define NH 8
#define CH 32
#define HC 256

typedef unsigned short u16;
typedef __attribute__((ext_vector_type(8))) __bf16 bf16x8;
typedef __attribute__((ext_vector_type(4))) float f32x4;

static __device__ __forceinline__ u16 f2bf(float f) {
    unsigned int u = __float_as_uint(f);
    unsigned int r = (u + 0x7fffu + ((u >> 16) & 1u)) >> 16;
    return (u16)r;
}
static __device__ __forceinline__ float bf2f(u16 h) {
    return __uint_as_float(((unsigned int)h) << 16);
}
static __device__ __forceinline__ void split2(float f, u16& hi, u16& lo) {
    hi = f2bf(f);
    lo = f2bf(f - bf2f(hi));
}

// ---------------------------------------------------------------------------
// Prep: w_v, w_g -> bf16 hi/lo K-major (wvT[n][c] = w_v[c][n], n<256,c<64);
//       w_b -> wbT[n][c] = w_b[c][n] (n<16 padded, c<128), hi/lo.
// ---------------------------------------------------------------------------
__global__ __launch_bounds__(256) void kW_prep(
    const float* __restrict__ wv, const float* __restrict__ wg,
    const float* __restrict__ wb,
    u16* __restrict__ wvT_hi, u16* __restrict__ wvT_lo,
    u16* __restrict__ wgT_hi, u16* __restrict__ wgT_lo,
    u16* __restrict__ wbT_hi, u16* __restrict__ wbT_lo)
{
    const int idx = blockIdx.x * 256 + threadIdx.x;
    if (idx < 16384) {
        const int n = idx >> 6, c = idx & 63;
        split2(wv[c * HC + n], wvT_hi[idx], wvT_lo[idx]);
    } else if (idx < 32768) {
        const int r = idx - 16384;
        const int n = r >> 6, c = r & 63;
        split2(wg[c * HC + n], wgT_hi[r], wgT_lo[r]);
    } else if (idx < 34816) {
        const int r = idx - 32768;
        const int n = r >> 7, c = r & 127;
        split2(n < NH ? wb[c * NH + n] : 0.f, wbT_hi[r], wbT_lo[r]);
    }
}

// ---------------------------------------------------------------------------
// Kernel A1 (split-MFMA): bias[h][row] = LN(z[row,:]) @ w_b[:,h] + INF*(mask-1)
// ---------------------------------------------------------------------------
__global__ __launch_bounds__(256) void kA1_bias(
    const float* __restrict__ z, const float* __restrict__ z_mask,
    const float* __restrict__ ln_z_g, const float* __restrict__ ln_z_b,
    const u16* __restrict__ wbT_hi, const u16* __restrict__ wbT_lo,
    float* __restrict__ bias_ws)
{
    __shared__ __align__(16) u16 a_hi[128 * 136];
    __shared__ __align__(16) u16 a_lo[128 * 136];
    __shared__ __align__(16) u16 b_hi[16 * 136];
    __shared__ __align__(16) u16 b_lo[16 * 136];
    const int tid  = threadIdx.x;
    const int lane = tid & 63, w = tid >> 6;
    const int row0 = blockIdx.x * 128;

    {
        const int r = tid >> 1, half = tid & 1;
        const float* src = z + (size_t)(row0 + r) * CZ + half * 64;
        float x[64];
        float s1 = 0.f, s2 = 0.f;
        #pragma unroll
        for (int e = 0; e < 16; ++e) {
            float4 v4 = *reinterpret_cast<const float4*>(src + e * 4);
            x[e*4+0] = v4.x; x[e*4+1] = v4.y; x[e*4+2] = v4.z; x[e*4+3] = v4.w;
            s1 += v4.x + v4.y + v4.z + v4.w;
            s2 += v4.x*v4.x + v4.y*v4.y + v4.z*v4.z + v4.w*v4.w;
        }
        s1 += __shfl_xor(s1, 1);
        s2 += __shfl_xor(s2, 1);
        const float mu   = s1 * (1.f / CZ);
        const float var  = s2 * (1.f / CZ) - mu * mu;
        const float rstd = rsqrtf(var + 1e-5f);
        #pragma unroll
        for (int e = 0; e < 16; ++e) {
            float4 g4 = *reinterpret_cast<const float4*>(ln_z_g + half * 64 + e * 4);
            float4 b4 = *reinterpret_cast<const float4*>(ln_z_b + half * 64 + e * 4);
            const int c = half * 64 + e * 4;
            split2((x[e*4+0] - mu) * rstd * g4.x + b4.x,
                   a_hi[r * 136 + c + 0], a_lo[r * 136 + c + 0]);
            split2((x[e*4+1] - mu) * rstd * g4.y + b4.y,
                   a_hi[r * 136 + c + 1], a_lo[r * 136 + c + 1]);
            split2((x[e*4+2] - mu) * rstd * g4.z + b4.z,
                   a_hi[r * 136 + c + 2], a_lo[r * 136 + c + 2]);
            split2((x[e*4+3] - mu) * rstd * g4.w + b4.w,
                   a_hi[r * 136 + c + 3], a_lo[r * 136 + c + 3]);
        }
    }
    {
        const int row = tid >> 4, off = (tid & 15) * 8;
        *reinterpret_cast<uint4*>(&b_hi[row * 136 + off]) =
            *reinterpret_cast<const uint4*>(wbT_hi + row * 128 + off);
        *reinterpret_cast<uint4*>(&b_lo[row * 136 + off]) =
            *reinterpret_cast<const uint4*>(wbT_lo + row * 128 + off);
    }
    __syncthreads();

    const int wr = w * 32;
    f32x4 acc[2] = {};
    #pragma unroll
    for (int ks = 0; ks < 4; ++ks) {
        const int ko = ks * 32 + (lane >> 4) * 8;
        bf16x8 bh = *reinterpret_cast<const bf16x8*>(&b_hi[(lane & 15) * 136 + ko]);
        bf16x8 bl = *reinterpret_cast<const bf16x8*>(&b_lo[(lane & 15) * 136 + ko]);
        #pragma unroll
        for (int mm = 0; mm < 2; ++mm) {
            const int base = (wr + mm * 16 + (lane & 15)) * 136 + ko;
            bf16x8 ah = *reinterpret_cast<const bf16x8*>(&a_hi[base]);
            bf16x8 al = *reinterpret_cast<const bf16x8*>(&a_lo[base]);
            acc[mm] = __builtin_amdgcn_mfma_f32_16x16x32_bf16(ah, bh, acc[mm], 0, 0, 0);
            acc[mm] = __builtin_amdgcn_mfma_f32_16x16x32_bf16(al, bh, acc[mm], 0, 0, 0);
            acc[mm] = __builtin_amdgcn_mfma_f32_16x16x32_bf16(ah, bl, acc[mm], 0, 0, 0);
        }
    }

    __syncthreads();
    float* T = reinterpret_cast<float*>(a_hi);      // [8 h][132 rows] f32
    const int cl = lane & 15, r4 = (lane >> 4) * 4;
    #pragma unroll
    for (int mm = 0; mm < 2; ++mm) {
        if (cl < NH) {
            #pragma unroll
            for (int r = 0; r < 4; ++r)
                T[cl * 132 + wr + mm * 16 + r4 + r] = acc[mm][r];
        }
    }
    __syncthreads();
    {
        const int h = tid >> 5, q = (tid & 31) * 4;
        float4 v  = *reinterpret_cast<const float4*>(&T[h * 132 + q]);
        float4 mk = *reinterpret_cast<const float4*>(z_mask + row0 + q);
        v.x += 1e8f * (mk.x - 1.f);
        v.y += 1e8f * (mk.y - 1.f);
        v.z += 1e8f * (mk.z - 1.f);
        v.w += 1e8f * (mk.w - 1.f);
        *reinterpret_cast<float4*>(
            &bias_ws[(size_t)h * R_DIM * R_DIM + row0 + q]) = v;
    }
}

// ---------------------------------------------------------------------------
// Kernel A2: w_soft[h][i][j] = softmax_j(bias[h][i][j]) -> bf16
// ---------------------------------------------------------------------------
__global__ __launch_bounds__(256) void kA2_softmax(
    const float* __restrict__ bias_ws, u16* __restrict__ w_soft)
{
    const int tid = threadIdx.x, w = tid >> 6, lane = tid & 63;
    const int row = blockIdx.x * 4 + w;           // h*R + i
    const float* src = bias_ws + (size_t)row * R_DIM;
    float vals[6];
    float mx = -1e30f;
    #pragma unroll
    for (int u = 0; u < 6; ++u) {
        vals[u] = src[lane + u * 64];
        mx = fmaxf(mx, vals[u]);
    }
    #pragma unroll
    for (int msk = 32; msk >= 1; msk >>= 1) mx = fmaxf(mx, __shfl_xor(mx, msk));
    float sum = 0.f;
    #pragma unroll
    for (int u = 0; u < 6; ++u) { vals[u] = __expf(vals[u] - mx); sum += vals[u]; }
    #pragma unroll
    for (int msk = 32; msk >= 1; msk >>= 1) sum += __shfl_xor(sum, msk);
    const float inv = 1.0f / sum;
    u16* dst = w_soft + (size_t)row * R_DIM;
    #pragma unroll
    for (int u = 0; u < 6; ++u)
        dst[lane + u * 64] = f2bf(vals[u] * inv);
}

// ---------------------------------------------------------------------------
// Kernel B (split-MFMA, merged, race-free): stage+LN+split A ONCE (LDS),
// loop 4 weight tiles; B fragments direct from global (L2-resident weights).
// ---------------------------------------------------------------------------
__global__ __launch_bounds__(256) void kB_mfma(
    const float* __restrict__ m_chunk, const float* __restrict__ mask_chunk,
    const float* __restrict__ ln_g, const float* __restrict__ ln_b,
    const u16* __restrict__ wvT_hi, const u16* __restrict__ wvT_lo,
    const u16* __restrict__ wgT_hi, const u16* __restrict__ wgT_lo,
    u16* __restrict__ Vt, u16* __restrict__ gbuf, int SCH)
{
    __shared__ __align__(16) u16 a_hi[128 * 72];
    __shared__ __align__(16) u16 a_lo[128 * 72];
    __shared__ __align__(16) u16 Tbuf[128 * 136];
    const int tid  = threadIdx.x;
    const int si0  = blockIdx.x * 128;
    const int lane = tid & 63;
    const int w    = tid >> 6;
    const int wr   = (w >> 1) * 64, wc = (w & 1) * 64;

    {
        const int r = tid >> 1, half = tid & 1;
        const float* src = m_chunk + (size_t)(si0 + r) * CM + half * 32;
        float x[32];
        float s1 = 0.f, s2 = 0.f;
        #pragma unroll
        for (int e = 0; e < 8; ++e) {
            float4 v4 = *reinterpret_cast<const float4*>(src + e * 4);
            x[e*4+0] = v4.x; x[e*4+1] = v4.y; x[e*4+2] = v4.z; x[e*4+3] = v4.w;
            s1 += v4.x + v4.y + v4.z + v4.w;
            s2 += v4.x*v4.x + v4.y*v4.y + v4.z*v4.z + v4.w*v4.w;
        }
        s1 += __shfl_xor(s1, 1);
        s2 += __shfl_xor(s2, 1);
        const float mu   = s1 * (1.f / 64);
        const float var  = s2 * (1.f / 64) - mu * mu;
        const float rstd = rsqrtf(var + 1e-5f);
        u16 ph[32], pl[32];
        #pragma unroll
        for (int e = 0; e < 8; ++e) {
            #pragma unroll
            for (int q = 0; q < 4; ++q) {
                const int cl_ = e * 4 + q;
                const int c = half * 32 + cl_;
                const float v = (x[cl_] - mu) * rstd * ln_g[c] + ln_b[c];
                split2(v, ph[cl_], pl[cl_]);
            }
        }
        u16* dh = &a_hi[r * 72 + half * 32];
        u16* dl = &a_lo[r * 72 + half * 32];
        #pragma unroll
        for (int e = 0; e < 4; ++e) {
            *reinterpret_cast<uint4*>(dh + e * 8) =
                reinterpret_cast<const uint4*>(ph)[e];
            *reinterpret_cast<uint4*>(dl + e * 8) =
                reinterpret_cast<const uint4*>(pl)[e];
        }
    }
    __syncthreads();    // A visible to all waves; never rewritten after this

    #pragma unroll
    for (int t = 0; t < 4; ++t) {
        const int n0   = (t & 1) * 128;
        const bool isV = (t < 2);
        const u16* Wh = (isV ? wvT_hi : wgT_hi) + (size_t)n0 * 64;
        const u16* Wl = (isV ? wvT_lo : wgT_lo) + (size_t)n0 * 64;

        f32x4 acc[4][4] = {};
        #pragma unroll
        for (int ks = 0; ks < 2; ++ks) {
            const int ko = ks * 32 + (lane >> 4) * 8;
            bf16x8 ah[4], al[4], bh[4], bl[4];
            #pragma unroll
            for (int nn = 0; nn < 4; ++nn) {
                const size_t base = (size_t)(wc + nn * 16 + (lane & 15)) * 64 + ko;
                bh[nn] = *reinterpret_cast<const bf16x8*>(Wh + base);
                bl[nn] = *reinterpret_cast<const bf16x8*>(Wl + base);
            }
            #pragma unroll
            for (int mm = 0; mm < 4; ++mm) {
                const int abase = (wr + mm * 16 + (lane & 15)) * 72 + ko;
                ah[mm] = *reinterpret_cast<const bf16x8*>(&a_hi[abase]);
                al[mm] = *reinterpret_cast<const bf16x8*>(&a_lo[abase]);
            }
            #pragma unroll
            for (int mm = 0; mm < 4; ++mm)
                #pragma unroll
                for (int nn = 0; nn < 4; ++nn) {
                    acc[mm][nn] = __builtin_amdgcn_mfma_f32_16x16x32_bf16(
                        ah[mm], bh[nn], acc[mm][nn], 0, 0, 0);
                    acc[mm][nn] = __builtin_amdgcn_mfma_f32_16x16x32_bf16(
                        al[mm], bh[nn], acc[mm][nn], 0, 0, 0);
                    acc[mm][nn] = __builtin_amdgcn_mfma_f32_16x16x32_bf16(
                        ah[mm], bl[nn], acc[mm][nn], 0, 0, 0);
                }
        }
        __syncthreads();   // prior tile's Tbuf readers are done (no-op at t=0)

        const int r4 = (lane >> 4) * 4, cl = lane & 15;
        if (isV) {
            #pragma unroll
            for (int mm = 0; mm < 4; ++mm) {
                const int rowb = wr + mm * 16 + r4;
                const float4 mk =
                    *reinterpret_cast<const float4*>(mask_chunk + si0 + rowb);
                #pragma unroll
                for (int nn = 0; nn < 4; ++nn) {
                    const int n = wc + nn * 16 + cl;
                    ushort4 pk;
                    pk.x = f2bf(acc[mm][nn][0] * mk.x);
                    pk.y = f2bf(acc[mm][nn][1] * mk.y);
                    pk.z = f2bf(acc[mm][nn][2] * mk.z);
                    pk.w = f2bf(acc[mm][nn][3] * mk.w);
                    *reinterpret_cast<ushort4*>(&Tbuf[n * 136 + rowb]) = pk;
                }
            }
            __syncthreads();
            const int sc = si0 / R_DIM, j0 = si0 % R_DIM;
            const size_t Nn = (size_t)SCH * 32;
            #pragma unroll
            for (int e = 0; e < 8; ++e) {
                const int c = e * 256 + tid;
                const int n = c >> 4, part = c & 15;
                const int k = n0 + n;
                const int h = k >> 5, cc = k & 31;
                u16* dst = Vt + ((size_t)h * Nn + (size_t)sc * 32 + cc) * R_DIM
                             + j0 + part * 8;
                *reinterpret_cast<uint4*>(dst) =
                    *reinterpret_cast<const uint4*>(&Tbuf[n * 136 + part * 8]);
            }
        } else {
            #pragma unroll
            for (int mm = 0; mm < 4; ++mm) {
                const int rowb = wr + mm * 16 + r4;
                #pragma unroll
                for (int nn = 0; nn < 4; ++nn) {
                    const int n = wc + nn * 16 + cl;
                    #pragma unroll
                    for (int r = 0; r < 4; ++r)
                        Tbuf[(rowb + r) * 136 + n] =
                            f2bf(1.f / (1.f + __expf(-acc[mm][nn][r])));
                }
            }
            __syncthreads();
            #pragma unroll
            for (int e = 0; e < 8; ++e) {
                const int c = e * 256 + tid;
                const int row = c >> 4, part = c & 15;
                u16* dst = gbuf + (size_t)(si0 + row) * HC + n0 + part * 8;
                *reinterpret_cast<uint4*>(dst) =
                    *reinterpret_cast<const uint4*>(&Tbuf[row * 136 + part * 8]);
            }
        }
    }
}

// ---------------------------------------------------------------------------
// Kernel C: per-head MFMA GEMM  o_pre[i,n] = sum_j W_h[i,j] * V_h[j,n]
// writes o_pre bf16 [sc*R + i][h*32+c]
// ---------------------------------------------------------------------------
__global__ __launch_bounds__(256) void kC_mfma(
    const u16* __restrict__ Wsoft, const u16* __restrict__ Vt,
    u16* __restrict__ o_pre, int SCH)
{
    constexpr int LDSP = 40;
    __shared__ __align__(16) u16 lds_a[128 * LDSP];
    __shared__ __align__(16) u16 lds_b[128 * LDSP];
    const int N   = SCH * 32;
    const int n0  = blockIdx.x * 128;
    const int i0  = blockIdx.y * 128;
    const int h   = blockIdx.z;
    const int tid = threadIdx.x;
    const int lane = tid & 63;
    const int w    = tid >> 6;
    const int wr   = (w >> 1) * 64;
    const int wc   = (w & 1) * 64;

    const u16* Wp = Wsoft + (size_t)h * R_DIM * R_DIM;
    const u16* Vp = Vt    + (size_t)h * N * R_DIM;

    f32x4 acc[4][4] = {};

    for (int k0 = 0; k0 < R_DIM; k0 += 32) {
        __syncthreads();
        #pragma unroll
        for (int rep = 0; rep < 2; ++rep) {
            const int c = rep * 256 + tid;
            const int row = c >> 2, q = c & 3;
            uint4 va = *reinterpret_cast<const uint4*>(
                Wp + (size_t)(i0 + row) * R_DIM + k0 + q * 8);
            *reinterpret_cast<uint4*>(&lds_a[row * LDSP + q * 8]) = va;
            uint4 vb = *reinterpret_cast<const uint4*>(
                Vp + (size_t)(n0 + row) * R_DIM + k0 + q * 8);
            *reinterpret_cast<uint4*>(&lds_b[row * LDSP + q * 8]) = vb;
        }
        __syncthreads();

        bf16x8 afrag[4], bfrag[4];
        #pragma unroll
        for (int mm = 0; mm < 4; ++mm) {
            const int row = wr + mm * 16 + (lane & 15);
            afrag[mm] = *reinterpret_cast<const bf16x8*>(
                &lds_a[row * LDSP + (lane >> 4) * 8]);
        }
        #pragma unroll
        for (int nn = 0; nn < 4; ++nn) {
            const int row = wc + nn * 16 + (lane & 15);
            bfrag[nn] = *reinterpret_cast<const bf16x8*>(
                &lds_b[row * LDSP + (lane >> 4) * 8]);
        }
        #pragma unroll
        for (int mm = 0; mm < 4; ++mm)
            #pragma unroll
            for (int nn = 0; nn < 4; ++nn)
                acc[mm][nn] = __builtin_amdgcn_mfma_f32_16x16x32_bf16(
                    afrag[mm], bfrag[nn], acc[mm][nn], 0, 0, 0);
    }

    const int r4 = (lane >> 4) * 4;
    const int cl = lane & 15;
    #pragma unroll
    for (int mm = 0; mm < 4; ++mm) {
        #pragma unroll
        for (int nn = 0; nn < 4; ++nn) {
            const int i = i0 + wr + mm * 16 + r4;
            const int n = n0 + wc + nn * 16 + cl;
            const int sc = n >> 5, cc = n & 31;
            u16* dst = &o_pre[((size_t)sc * R_DIM + i) * HC + h * 32 + cc];
            #pragma unroll
            for (int r = 0; r < 4; ++r)
                dst[(size_t)r * HC] = f2bf(acc[mm][nn][r]);
        }
    }
}

// ---------------------------------------------------------------------------
// Kernel D: out[si, :] = (g[si,:] * o_pre[si,:]) @ w_o  (K=256, N=64)
// fp32 VALU GEMM (proven); A-tile loads bf16 g/o, product in f32.
// ---------------------------------------------------------------------------
__global__ __launch_bounds__(256) void kD_out(
    const u16* __restrict__ gbuf, const u16* __restrict__ o_pre,
    const float* __restrict__ w_o, float* __restrict__ out_chunk, int SCH)
{
    __shared__ float A[128 * 65];
    __shared__ float Bt[64 * 64];
    const int si0 = blockIdx.x * 128;
    const int tid = threadIdx.x;
    const int tx  = tid & 15, ty = tid >> 4;
    float acc[8][4] = {};

    for (int k0 = 0; k0 < HC; k0 += 64) {
        { // A tile = g * o_pre (bf16 loads -> f32 product)
            const int r = tid >> 1, half = tid & 1;
            const size_t base = (size_t)(si0 + r) * HC + k0 + half * 32;
            float* dst = &A[r * 65 + half * 32];
            #pragma unroll
            for (int e = 0; e < 4; ++e) {
                uint4 gv = *reinterpret_cast<const uint4*>(gbuf + base + e * 8);
                uint4 ov = *reinterpret_cast<const uint4*>(o_pre + base + e * 8);
                const u16* ga = (const u16*)&gv;
                const u16* oa = (const u16*)&ov;
                #pragma unroll
                for (int q = 0; q < 8; ++q)
                    dst[e * 8 + q] = bf2f(ga[q]) * bf2f(oa[q]);
            }
        }
        { // w_o tile
            const int kk = tid >> 2, q = tid & 3;
            #pragma unroll
            for (int e = 0; e < 4; ++e) {
                float4 v4 = *reinterpret_cast<const float4*>(
                    w_o + (size_t)(k0 + kk) * CM + q * 16 + e * 4);
                *reinterpret_cast<float4*>(&Bt[kk * 64 + q * 16 + e * 4]) = v4;
            }
        }
        __syncthreads();
        #pragma unroll 8
        for (int kk = 0; kk < 64; ++kk) {
            float4 b = *reinterpret_cast<float4*>(&Bt[kk * 64 + tx * 4]);
            #pragma unroll
            for (int e = 0; e < 8; ++e) {
                float a = A[(ty * 8 + e) * 65 + kk];
                acc[e][0] += a * b.x; acc[e][1] += a * b.y;
                acc[e][2] += a * b.z; acc[e][3] += a * b.w;
            }
        }
        __syncthreads();
    }
    #pragma unroll
    for (int e = 0; e < 8; ++e) {
        *reinterpret_cast<float4*>(
            &out_chunk[(size_t)(si0 + ty * 8 + e) * CM + tx * 4]) =
            make_float4(acc[e][0], acc[e][1], acc[e][2], acc[e][3]);
    }
}

// ---------------------------------------------------------------------------
extern "C" void kernel_launch(void* const* d_in, const int* in_sizes, int n_in,
                              void* d_out, int out_size, void* d_ws, size_t ws_size,
                              hipStream_t stream)
{
    const float* m        = (const float*)d_in[0];
    const float* z        = (const float*)d_in[1];
    const float* msa_mask = (const float*)d_in[2];
    const float* z_mask   = (const float*)d_in[3];
    const float* ln_m_g   = (const float*)d_in[4];
    const float* ln_m_b   = (const float*)d_in[5];
    const float* w_v      = (const float*)d_in[6];
    const float* w_g      = (const float*)d_in[7];
    const float* ln_z_g   = (const float*)d_in[8];
    const float* ln_z_b   = (const float*)d_in[9];
    const float* w_b      = (const float*)d_in[10];
    const float* w_o      = (const float*)d_in[11];
    float* out = (float*)d_out;

    const size_t wsoft_bytes = (size_t)NH * R_DIM * R_DIM * 2;       // bf16
    const size_t bias_bytes  = (size_t)NH * R_DIM * R_DIM * 4;       // f32
    const size_t wts_bytes   = 4 * 16384 * 2 + 2 * 2048 * 2;
    // per s-row: Vt bf16 + g bf16 + o_pre bf16
    const size_t per_sch = (size_t)R_DIM * HC * (2 + 2 + 2);
    // SCH=128: per-chunk working set (~100 MB incl. m-chunk) fits the 256 MB
    // L3, and Vt/gbuf/obuf are re-written at the same addresses every chunk
    // -> intermediate writes/reads should be L3-absorbed instead of HBM.
    int SCH = 128;
    while (SCH > 4 &&
           wsoft_bytes + bias_bytes + wts_bytes + (size_t)SCH * per_sch > ws_size)
        SCH >>= 1;

    char* p = (char*)d_ws;
    u16* w_soft   = (u16*)p; p += wsoft_bytes;
    float* biasws = (float*)p; p += bias_bytes;
    u16* wvT_hi   = (u16*)p; p += 16384 * 2;
    u16* wvT_lo   = (u16*)p; p += 16384 * 2;
    u16* wgT_hi   = (u16*)p; p += 16384 * 2;
    u16* wgT_lo   = (u16*)p; p += 16384 * 2;
    u16* wbT_hi   = (u16*)p; p += 2048 * 2;
    u16* wbT_lo   = (u16*)p; p += 2048 * 2;
    u16* Vt       = (u16*)p; p += (size_t)SCH * 32 * NH * R_DIM * 2;
    u16* gbuf     = (u16*)p; p += (size_t)SCH * R_DIM * HC * 2;
    u16* obuf     = (u16*)p;

    kW_prep<<<136, 256, 0, stream>>>(w_v, w_g, w_b, wvT_hi, wvT_lo,
                                     wgT_hi, wgT_lo, wbT_hi, wbT_lo);
    kA1_bias<<<R_DIM * R_DIM / 128, 256, 0, stream>>>(
        z, z_mask, ln_z_g, ln_z_b, wbT_hi, wbT_lo, biasws);
    kA2_softmax<<<NH * R_DIM / 4, 256, 0, stream>>>(biasws, w_soft);

    for (int s0 = 0; s0 < S_DIM; s0 += SCH) {
        kB_mfma<<<dim3(SCH * 3), 256, 0, stream>>>(
            m + (size_t)s0 * R_DIM * CM, msa_mask + (size_t)s0 * R_DIM,
            ln_m_g, ln_m_b, wvT_hi, wvT_lo, wgT_hi, wgT_lo, Vt, gbuf, SCH);
        kC_mfma<<<dim3(SCH / 4, 3, NH), 256, 0, stream>>>(w_soft, Vt, obuf, SCH);
        kD_out<<<dim3(SCH * 3), 256, 0, stream>>>(gbuf, obuf, w_o,
                                                  out + (size_t)s0 * R_DIM * CM, SCH);
    }
}

// Round 17
// 317.435 us; speedup vs baseline: 1.2302x; 1.2302x over previous
//
#include <hip/hip_runtime.h>
#include <math.h>

#define S_DIM 512
#define R_DIM 384
#define CM 64
#define CZ 128
#define NH 8
#define CH 32
#define HC 256

typedef unsigned short u16;
typedef __attribute__((ext_vector_type(8))) __bf16 bf16x8;
typedef __attribute__((ext_vector_type(4))) float f32x4;

static __device__ __forceinline__ u16 f2bf(float f) {
    unsigned int u = __float_as_uint(f);
    unsigned int r = (u + 0x7fffu + ((u >> 16) & 1u)) >> 16;
    return (u16)r;
}
static __device__ __forceinline__ float bf2f(u16 h) {
    return __uint_as_float(((unsigned int)h) << 16);
}
static __device__ __forceinline__ void split2(float f, u16& hi, u16& lo) {
    hi = f2bf(f);
    lo = f2bf(f - bf2f(hi));
}

// ---------------------------------------------------------------------------
// Prep: w_v, w_g -> bf16 hi/lo K-major (wvT[n][c] = w_v[c][n], n<256,c<64);
//       w_b -> wbT[n][c] = w_b[c][n] (n<16 padded, c<128), hi/lo.
// ---------------------------------------------------------------------------
__global__ __launch_bounds__(256) void kW_prep(
    const float* __restrict__ wv, const float* __restrict__ wg,
    const float* __restrict__ wb,
    u16* __restrict__ wvT_hi, u16* __restrict__ wvT_lo,
    u16* __restrict__ wgT_hi, u16* __restrict__ wgT_lo,
    u16* __restrict__ wbT_hi, u16* __restrict__ wbT_lo)
{
    const int idx = blockIdx.x * 256 + threadIdx.x;
    if (idx < 16384) {
        const int n = idx >> 6, c = idx & 63;
        split2(wv[c * HC + n], wvT_hi[idx], wvT_lo[idx]);
    } else if (idx < 32768) {
        const int r = idx - 16384;
        const int n = r >> 6, c = r & 63;
        split2(wg[c * HC + n], wgT_hi[r], wgT_lo[r]);
    } else if (idx < 34816) {
        const int r = idx - 32768;
        const int n = r >> 7, c = r & 127;
        split2(n < NH ? wb[c * NH + n] : 0.f, wbT_hi[r], wbT_lo[r]);
    }
}

// ---------------------------------------------------------------------------
// Kernel A1 (split-MFMA): bias[h][row] = LN(z[row,:]) @ w_b[:,h] + INF*(mask-1)
// ---------------------------------------------------------------------------
__global__ __launch_bounds__(256) void kA1_bias(
    const float* __restrict__ z, const float* __restrict__ z_mask,
    const float* __restrict__ ln_z_g, const float* __restrict__ ln_z_b,
    const u16* __restrict__ wbT_hi, const u16* __restrict__ wbT_lo,
    float* __restrict__ bias_ws)
{
    __shared__ __align__(16) u16 a_hi[128 * 136];
    __shared__ __align__(16) u16 a_lo[128 * 136];
    __shared__ __align__(16) u16 b_hi[16 * 136];
    __shared__ __align__(16) u16 b_lo[16 * 136];
    const int tid  = threadIdx.x;
    const int lane = tid & 63, w = tid >> 6;
    const int row0 = blockIdx.x * 128;

    {
        const int r = tid >> 1, half = tid & 1;
        const float* src = z + (size_t)(row0 + r) * CZ + half * 64;
        float x[64];
        float s1 = 0.f, s2 = 0.f;
        #pragma unroll
        for (int e = 0; e < 16; ++e) {
            float4 v4 = *reinterpret_cast<const float4*>(src + e * 4);
            x[e*4+0] = v4.x; x[e*4+1] = v4.y; x[e*4+2] = v4.z; x[e*4+3] = v4.w;
            s1 += v4.x + v4.y + v4.z + v4.w;
            s2 += v4.x*v4.x + v4.y*v4.y + v4.z*v4.z + v4.w*v4.w;
        }
        s1 += __shfl_xor(s1, 1);
        s2 += __shfl_xor(s2, 1);
        const float mu   = s1 * (1.f / CZ);
        const float var  = s2 * (1.f / CZ) - mu * mu;
        const float rstd = rsqrtf(var + 1e-5f);
        #pragma unroll
        for (int e = 0; e < 16; ++e) {
            float4 g4 = *reinterpret_cast<const float4*>(ln_z_g + half * 64 + e * 4);
            float4 b4 = *reinterpret_cast<const float4*>(ln_z_b + half * 64 + e * 4);
            const int c = half * 64 + e * 4;
            split2((x[e*4+0] - mu) * rstd * g4.x + b4.x,
                   a_hi[r * 136 + c + 0], a_lo[r * 136 + c + 0]);
            split2((x[e*4+1] - mu) * rstd * g4.y + b4.y,
                   a_hi[r * 136 + c + 1], a_lo[r * 136 + c + 1]);
            split2((x[e*4+2] - mu) * rstd * g4.z + b4.z,
                   a_hi[r * 136 + c + 2], a_lo[r * 136 + c + 2]);
            split2((x[e*4+3] - mu) * rstd * g4.w + b4.w,
                   a_hi[r * 136 + c + 3], a_lo[r * 136 + c + 3]);
        }
    }
    {
        const int row = tid >> 4, off = (tid & 15) * 8;
        *reinterpret_cast<uint4*>(&b_hi[row * 136 + off]) =
            *reinterpret_cast<const uint4*>(wbT_hi + row * 128 + off);
        *reinterpret_cast<uint4*>(&b_lo[row * 136 + off]) =
            *reinterpret_cast<const uint4*>(wbT_lo + row * 128 + off);
    }
    __syncthreads();

    const int wr = w * 32;
    f32x4 acc[2] = {};
    #pragma unroll
    for (int ks = 0; ks < 4; ++ks) {
        const int ko = ks * 32 + (lane >> 4) * 8;
        bf16x8 bh = *reinterpret_cast<const bf16x8*>(&b_hi[(lane & 15) * 136 + ko]);
        bf16x8 bl = *reinterpret_cast<const bf16x8*>(&b_lo[(lane & 15) * 136 + ko]);
        #pragma unroll
        for (int mm = 0; mm < 2; ++mm) {
            const int base = (wr + mm * 16 + (lane & 15)) * 136 + ko;
            bf16x8 ah = *reinterpret_cast<const bf16x8*>(&a_hi[base]);
            bf16x8 al = *reinterpret_cast<const bf16x8*>(&a_lo[base]);
            acc[mm] = __builtin_amdgcn_mfma_f32_16x16x32_bf16(ah, bh, acc[mm], 0, 0, 0);
            acc[mm] = __builtin_amdgcn_mfma_f32_16x16x32_bf16(al, bh, acc[mm], 0, 0, 0);
            acc[mm] = __builtin_amdgcn_mfma_f32_16x16x32_bf16(ah, bl, acc[mm], 0, 0, 0);
        }
    }

    __syncthreads();
    float* T = reinterpret_cast<float*>(a_hi);      // [8 h][132 rows] f32
    const int cl = lane & 15, r4 = (lane >> 4) * 4;
    #pragma unroll
    for (int mm = 0; mm < 2; ++mm) {
        if (cl < NH) {
            #pragma unroll
            for (int r = 0; r < 4; ++r)
                T[cl * 132 + wr + mm * 16 + r4 + r] = acc[mm][r];
        }
    }
    __syncthreads();
    {
        const int h = tid >> 5, q = (tid & 31) * 4;
        float4 v  = *reinterpret_cast<const float4*>(&T[h * 132 + q]);
        float4 mk = *reinterpret_cast<const float4*>(z_mask + row0 + q);
        v.x += 1e8f * (mk.x - 1.f);
        v.y += 1e8f * (mk.y - 1.f);
        v.z += 1e8f * (mk.z - 1.f);
        v.w += 1e8f * (mk.w - 1.f);
        *reinterpret_cast<float4*>(
            &bias_ws[(size_t)h * R_DIM * R_DIM + row0 + q]) = v;
    }
}

// ---------------------------------------------------------------------------
// Kernel A2: w_soft[h][i][j] = softmax_j(bias[h][i][j]) -> bf16
// ---------------------------------------------------------------------------
__global__ __launch_bounds__(256) void kA2_softmax(
    const float* __restrict__ bias_ws, u16* __restrict__ w_soft)
{
    const int tid = threadIdx.x, w = tid >> 6, lane = tid & 63;
    const int row = blockIdx.x * 4 + w;           // h*R + i
    const float* src = bias_ws + (size_t)row * R_DIM;
    float vals[6];
    float mx = -1e30f;
    #pragma unroll
    for (int u = 0; u < 6; ++u) {
        vals[u] = src[lane + u * 64];
        mx = fmaxf(mx, vals[u]);
    }
    #pragma unroll
    for (int msk = 32; msk >= 1; msk >>= 1) mx = fmaxf(mx, __shfl_xor(mx, msk));
    float sum = 0.f;
    #pragma unroll
    for (int u = 0; u < 6; ++u) { vals[u] = __expf(vals[u] - mx); sum += vals[u]; }
    #pragma unroll
    for (int msk = 32; msk >= 1; msk >>= 1) sum += __shfl_xor(sum, msk);
    const float inv = 1.0f / sum;
    u16* dst = w_soft + (size_t)row * R_DIM;
    #pragma unroll
    for (int u = 0; u < 6; ++u)
        dst[lane + u * 64] = f2bf(vals[u] * inv);
}

// ---------------------------------------------------------------------------
// Kernel B (split-MFMA, merged, race-free): stage+LN+split A ONCE (LDS),
// loop 4 weight tiles; B fragments direct from global (L2-resident weights).
// NEW: wave-contiguous output layouts.
//   Vt[h][jblk][n][jloc<128>]  (jblk = block's 128-j slice)  -> 4 KB/256thr
//   g [kblk][si][kloc<128>]    (kblk = n0>>7)                -> 4 KB/256thr
// ---------------------------------------------------------------------------
__global__ __launch_bounds__(256) void kB_mfma(
    const float* __restrict__ m_chunk, const float* __restrict__ mask_chunk,
    const float* __restrict__ ln_g, const float* __restrict__ ln_b,
    const u16* __restrict__ wvT_hi, const u16* __restrict__ wvT_lo,
    const u16* __restrict__ wgT_hi, const u16* __restrict__ wgT_lo,
    u16* __restrict__ Vt, u16* __restrict__ gbuf, int SCH)
{
    __shared__ __align__(16) u16 a_hi[128 * 72];
    __shared__ __align__(16) u16 a_lo[128 * 72];
    __shared__ __align__(16) u16 Tbuf[128 * 136];
    const int tid  = threadIdx.x;
    const int si0  = blockIdx.x * 128;
    const int lane = tid & 63;
    const int w    = tid >> 6;
    const int wr   = (w >> 1) * 64, wc = (w & 1) * 64;

    {
        const int r = tid >> 1, half = tid & 1;
        const float* src = m_chunk + (size_t)(si0 + r) * CM + half * 32;
        float x[32];
        float s1 = 0.f, s2 = 0.f;
        #pragma unroll
        for (int e = 0; e < 8; ++e) {
            float4 v4 = *reinterpret_cast<const float4*>(src + e * 4);
            x[e*4+0] = v4.x; x[e*4+1] = v4.y; x[e*4+2] = v4.z; x[e*4+3] = v4.w;
            s1 += v4.x + v4.y + v4.z + v4.w;
            s2 += v4.x*v4.x + v4.y*v4.y + v4.z*v4.z + v4.w*v4.w;
        }
        s1 += __shfl_xor(s1, 1);
        s2 += __shfl_xor(s2, 1);
        const float mu   = s1 * (1.f / 64);
        const float var  = s2 * (1.f / 64) - mu * mu;
        const float rstd = rsqrtf(var + 1e-5f);
        u16 ph[32], pl[32];
        #pragma unroll
        for (int e = 0; e < 8; ++e) {
            #pragma unroll
            for (int q = 0; q < 4; ++q) {
                const int cl_ = e * 4 + q;
                const int c = half * 32 + cl_;
                const float v = (x[cl_] - mu) * rstd * ln_g[c] + ln_b[c];
                split2(v, ph[cl_], pl[cl_]);
            }
        }
        u16* dh = &a_hi[r * 72 + half * 32];
        u16* dl = &a_lo[r * 72 + half * 32];
        #pragma unroll
        for (int e = 0; e < 4; ++e) {
            *reinterpret_cast<uint4*>(dh + e * 8) =
                reinterpret_cast<const uint4*>(ph)[e];
            *reinterpret_cast<uint4*>(dl + e * 8) =
                reinterpret_cast<const uint4*>(pl)[e];
        }
    }
    __syncthreads();    // A visible to all waves; never rewritten after this

    #pragma unroll
    for (int t = 0; t < 4; ++t) {
        const int n0   = (t & 1) * 128;
        const bool isV = (t < 2);
        const u16* Wh = (isV ? wvT_hi : wgT_hi) + (size_t)n0 * 64;
        const u16* Wl = (isV ? wvT_lo : wgT_lo) + (size_t)n0 * 64;

        f32x4 acc[4][4] = {};
        #pragma unroll
        for (int ks = 0; ks < 2; ++ks) {
            const int ko = ks * 32 + (lane >> 4) * 8;
            bf16x8 ah[4], al[4], bh[4], bl[4];
            #pragma unroll
            for (int nn = 0; nn < 4; ++nn) {
                const size_t base = (size_t)(wc + nn * 16 + (lane & 15)) * 64 + ko;
                bh[nn] = *reinterpret_cast<const bf16x8*>(Wh + base);
                bl[nn] = *reinterpret_cast<const bf16x8*>(Wl + base);
            }
            #pragma unroll
            for (int mm = 0; mm < 4; ++mm) {
                const int abase = (wr + mm * 16 + (lane & 15)) * 72 + ko;
                ah[mm] = *reinterpret_cast<const bf16x8*>(&a_hi[abase]);
                al[mm] = *reinterpret_cast<const bf16x8*>(&a_lo[abase]);
            }
            #pragma unroll
            for (int mm = 0; mm < 4; ++mm)
                #pragma unroll
                for (int nn = 0; nn < 4; ++nn) {
                    acc[mm][nn] = __builtin_amdgcn_mfma_f32_16x16x32_bf16(
                        ah[mm], bh[nn], acc[mm][nn], 0, 0, 0);
                    acc[mm][nn] = __builtin_amdgcn_mfma_f32_16x16x32_bf16(
                        al[mm], bh[nn], acc[mm][nn], 0, 0, 0);
                    acc[mm][nn] = __builtin_amdgcn_mfma_f32_16x16x32_bf16(
                        ah[mm], bl[nn], acc[mm][nn], 0, 0, 0);
                }
        }
        __syncthreads();   // prior tile's Tbuf readers are done (no-op at t=0)

        const int r4 = (lane >> 4) * 4, cl = lane & 15;
        if (isV) {
            #pragma unroll
            for (int mm = 0; mm < 4; ++mm) {
                const int rowb = wr + mm * 16 + r4;
                const float4 mk =
                    *reinterpret_cast<const float4*>(mask_chunk + si0 + rowb);
                #pragma unroll
                for (int nn = 0; nn < 4; ++nn) {
                    const int n = wc + nn * 16 + cl;
                    ushort4 pk;
                    pk.x = f2bf(acc[mm][nn][0] * mk.x);
                    pk.y = f2bf(acc[mm][nn][1] * mk.y);
                    pk.z = f2bf(acc[mm][nn][2] * mk.z);
                    pk.w = f2bf(acc[mm][nn][3] * mk.w);
                    *reinterpret_cast<ushort4*>(&Tbuf[n * 136 + rowb]) = pk;
                }
            }
            __syncthreads();
            const int sc   = si0 / R_DIM;
            const int jblk = (si0 % R_DIM) >> 7;
            const size_t Nn = (size_t)SCH * 32;
            #pragma unroll
            for (int e = 0; e < 8; ++e) {
                const int c = e * 256 + tid;
                const int n = c >> 4, part = c & 15;
                const int k = n0 + n;
                const int h = k >> 5, cc = k & 31;
                u16* dst = Vt + (((size_t)h * 3 + jblk) * Nn
                                 + (size_t)sc * 32 + cc) * 128 + part * 8;
                *reinterpret_cast<uint4*>(dst) =
                    *reinterpret_cast<const uint4*>(&Tbuf[n * 136 + part * 8]);
            }
        } else {
            #pragma unroll
            for (int mm = 0; mm < 4; ++mm) {
                const int rowb = wr + mm * 16 + r4;
                #pragma unroll
                for (int nn = 0; nn < 4; ++nn) {
                    const int n = wc + nn * 16 + cl;
                    #pragma unroll
                    for (int r = 0; r < 4; ++r)
                        Tbuf[(rowb + r) * 136 + n] =
                            f2bf(1.f / (1.f + __expf(-acc[mm][nn][r])));
                }
            }
            __syncthreads();
            const int kblk = n0 >> 7;
            const size_t SR = (size_t)SCH * R_DIM;
            #pragma unroll
            for (int e = 0; e < 8; ++e) {
                const int c = e * 256 + tid;
                const int row = c >> 4, part = c & 15;
                u16* dst = gbuf + ((size_t)kblk * SR + si0 + row) * 128 + part * 8;
                *reinterpret_cast<uint4*>(dst) =
                    *reinterpret_cast<const uint4*>(&Tbuf[row * 136 + part * 8]);
            }
        }
    }
}

// ---------------------------------------------------------------------------
// Kernel C: per-head MFMA GEMM  o_pre[i,n] = sum_j W_h[i,j] * V_h[j,n]
// Vt layout [h][jblk][n][jloc<128>]; writes o_pre bf16 [sc*R + i][h*32+c]
// ---------------------------------------------------------------------------
__global__ __launch_bounds__(256) void kC_mfma(
    const u16* __restrict__ Wsoft, const u16* __restrict__ Vt,
    u16* __restrict__ o_pre, int SCH)
{
    constexpr int LDSP = 40;
    __shared__ __align__(16) u16 lds_a[128 * LDSP];
    __shared__ __align__(16) u16 lds_b[128 * LDSP];
    const int N   = SCH * 32;
    const int n0  = blockIdx.x * 128;
    const int i0  = blockIdx.y * 128;
    const int h   = blockIdx.z;
    const int tid = threadIdx.x;
    const int lane = tid & 63;
    const int w    = tid >> 6;
    const int wr   = (w >> 1) * 64;
    const int wc   = (w & 1) * 64;

    const u16* Wp = Wsoft + (size_t)h * R_DIM * R_DIM;
    const u16* Vp = Vt    + (size_t)h * 3 * N * 128;

    f32x4 acc[4][4] = {};

    for (int k0 = 0; k0 < R_DIM; k0 += 32) {
        __syncthreads();
        const int jblk = k0 >> 7, jloc = k0 & 127;
        #pragma unroll
        for (int rep = 0; rep < 2; ++rep) {
            const int c = rep * 256 + tid;
            const int row = c >> 2, q = c & 3;
            uint4 va = *reinterpret_cast<const uint4*>(
                Wp + (size_t)(i0 + row) * R_DIM + k0 + q * 8);
            *reinterpret_cast<uint4*>(&lds_a[row * LDSP + q * 8]) = va;
            uint4 vb = *reinterpret_cast<const uint4*>(
                Vp + ((size_t)jblk * N + n0 + row) * 128 + jloc + q * 8);
            *reinterpret_cast<uint4*>(&lds_b[row * LDSP + q * 8]) = vb;
        }
        __syncthreads();

        bf16x8 afrag[4], bfrag[4];
        #pragma unroll
        for (int mm = 0; mm < 4; ++mm) {
            const int row = wr + mm * 16 + (lane & 15);
            afrag[mm] = *reinterpret_cast<const bf16x8*>(
                &lds_a[row * LDSP + (lane >> 4) * 8]);
        }
        #pragma unroll
        for (int nn = 0; nn < 4; ++nn) {
            const int row = wc + nn * 16 + (lane & 15);
            bfrag[nn] = *reinterpret_cast<const bf16x8*>(
                &lds_b[row * LDSP + (lane >> 4) * 8]);
        }
        #pragma unroll
        for (int mm = 0; mm < 4; ++mm)
            #pragma unroll
            for (int nn = 0; nn < 4; ++nn)
                acc[mm][nn] = __builtin_amdgcn_mfma_f32_16x16x32_bf16(
                    afrag[mm], bfrag[nn], acc[mm][nn], 0, 0, 0);
    }

    const int r4 = (lane >> 4) * 4;
    const int cl = lane & 15;
    #pragma unroll
    for (int mm = 0; mm < 4; ++mm) {
        #pragma unroll
        for (int nn = 0; nn < 4; ++nn) {
            const int i = i0 + wr + mm * 16 + r4;
            const int n = n0 + wc + nn * 16 + cl;
            const int sc = n >> 5, cc = n & 31;
            u16* dst = &o_pre[((size_t)sc * R_DIM + i) * HC + h * 32 + cc];
            #pragma unroll
            for (int r = 0; r < 4; ++r)
                dst[(size_t)r * HC] = f2bf(acc[mm][nn][r]);
        }
    }
}

// ---------------------------------------------------------------------------
// Kernel D: out[si, :] = (g[si,:] * o_pre[si,:]) @ w_o  (K=256, N=64)
// g layout [kblk][si][kloc<128>]; fp32 VALU GEMM (proven).
// ---------------------------------------------------------------------------
__global__ __launch_bounds__(256) void kD_out(
    const u16* __restrict__ gbuf, const u16* __restrict__ o_pre,
    const float* __restrict__ w_o, float* __restrict__ out_chunk, int SCH)
{
    __shared__ float A[128 * 65];
    __shared__ float Bt[64 * 64];
    const int si0 = blockIdx.x * 128;
    const int tid = threadIdx.x;
    const int tx  = tid & 15, ty = tid >> 4;
    const size_t SR = (size_t)SCH * R_DIM;
    float acc[8][4] = {};

    for (int k0 = 0; k0 < HC; k0 += 64) {
        { // A tile = g * o_pre (bf16 loads -> f32 product)
            const int r = tid >> 1, half = tid & 1;
            const size_t gb = ((size_t)(k0 >> 7) * SR + si0 + r) * 128
                              + (k0 & 127) + half * 32;
            const size_t ob = (size_t)(si0 + r) * HC + k0 + half * 32;
            float* dst = &A[r * 65 + half * 32];
            #pragma unroll
            for (int e = 0; e < 4; ++e) {
                uint4 gv = *reinterpret_cast<const uint4*>(gbuf + gb + e * 8);
                uint4 ov = *reinterpret_cast<const uint4*>(o_pre + ob + e * 8);
                const u16* ga = (const u16*)&gv;
                const u16* oa = (const u16*)&ov;
                #pragma unroll
                for (int q = 0; q < 8; ++q)
                    dst[e * 8 + q] = bf2f(ga[q]) * bf2f(oa[q]);
            }
        }
        { // w_o tile
            const int kk = tid >> 2, q = tid & 3;
            #pragma unroll
            for (int e = 0; e < 4; ++e) {
                float4 v4 = *reinterpret_cast<const float4*>(
                    w_o + (size_t)(k0 + kk) * CM + q * 16 + e * 4);
                *reinterpret_cast<float4*>(&Bt[kk * 64 + q * 16 + e * 4]) = v4;
            }
        }
        __syncthreads();
        #pragma unroll 8
        for (int kk = 0; kk < 64; ++kk) {
            float4 b = *reinterpret_cast<float4*>(&Bt[kk * 64 + tx * 4]);
            #pragma unroll
            for (int e = 0; e < 8; ++e) {
                float a = A[(ty * 8 + e) * 65 + kk];
                acc[e][0] += a * b.x; acc[e][1] += a * b.y;
                acc[e][2] += a * b.z; acc[e][3] += a * b.w;
            }
        }
        __syncthreads();
    }
    #pragma unroll
    for (int e = 0; e < 8; ++e) {
        *reinterpret_cast<float4*>(
            &out_chunk[(size_t)(si0 + ty * 8 + e) * CM + tx * 4]) =
            make_float4(acc[e][0], acc[e][1], acc[e][2], acc[e][3]);
    }
}

// ---------------------------------------------------------------------------
extern "C" void kernel_launch(void* const* d_in, const int* in_sizes, int n_in,
                              void* d_out, int out_size, void* d_ws, size_t ws_size,
                              hipStream_t stream)
{
    const float* m        = (const float*)d_in[0];
    const float* z        = (const float*)d_in[1];
    const float* msa_mask = (const float*)d_in[2];
    const float* z_mask   = (const float*)d_in[3];
    const float* ln_m_g   = (const float*)d_in[4];
    const float* ln_m_b   = (const float*)d_in[5];
    const float* w_v      = (const float*)d_in[6];
    const float* w_g      = (const float*)d_in[7];
    const float* ln_z_g   = (const float*)d_in[8];
    const float* ln_z_b   = (const float*)d_in[9];
    const float* w_b      = (const float*)d_in[10];
    const float* w_o      = (const float*)d_in[11];
    float* out = (float*)d_out;

    const size_t wsoft_bytes = (size_t)NH * R_DIM * R_DIM * 2;       // bf16
    const size_t bias_bytes  = (size_t)NH * R_DIM * R_DIM * 4;       // f32
    const size_t wts_bytes   = 4 * 16384 * 2 + 2 * 2048 * 2;
    // per s-row: Vt bf16 + g bf16 + o_pre bf16
    const size_t per_sch = (size_t)R_DIM * HC * (2 + 2 + 2);
    int SCH = 256;
    while (SCH > 4 &&
           wsoft_bytes + bias_bytes + wts_bytes + (size_t)SCH * per_sch > ws_size)
        SCH >>= 1;

    char* p = (char*)d_ws;
    u16* w_soft   = (u16*)p; p += wsoft_bytes;
    float* biasws = (float*)p; p += bias_bytes;
    u16* wvT_hi   = (u16*)p; p += 16384 * 2;
    u16* wvT_lo   = (u16*)p; p += 16384 * 2;
    u16* wgT_hi   = (u16*)p; p += 16384 * 2;
    u16* wgT_lo   = (u16*)p; p += 16384 * 2;
    u16* wbT_hi   = (u16*)p; p += 2048 * 2;
    u16* wbT_lo   = (u16*)p; p += 2048 * 2;
    u16* Vt       = (u16*)p; p += (size_t)SCH * 32 * NH * R_DIM * 2;
    u16* gbuf     = (u16*)p; p += (size_t)SCH * R_DIM * HC * 2;
    u16* obuf     = (u16*)p;

    kW_prep<<<136, 256, 0, stream>>>(w_v, w_g, w_b, wvT_hi, wvT_lo,
                                     wgT_hi, wgT_lo, wbT_hi, wbT_lo);
    kA1_bias<<<R_DIM * R_DIM / 128, 256, 0, stream>>>(
        z, z_mask, ln_z_g, ln_z_b, wbT_hi, wbT_lo, biasws);
    kA2_softmax<<<NH * R_DIM / 4, 256, 0, stream>>>(biasws, w_soft);

    for (int s0 = 0; s0 < S_DIM; s0 += SCH) {
        kB_mfma<<<dim3(SCH * 3), 256, 0, stream>>>(
            m + (size_t)s0 * R_DIM * CM, msa_mask + (size_t)s0 * R_DIM,
            ln_m_g, ln_m_b, wvT_hi, wvT_lo, wgT_hi, wgT_lo, Vt, gbuf, SCH);
        kC_mfma<<<dim3(SCH / 4, 3, NH), 256, 0, stream>>>(w_soft, Vt, obuf, SCH);
        kD_out<<<dim3(SCH * 3), 256, 0, stream>>>(gbuf, obuf, w_o,
                                                  out + (size_t)s0 * R_DIM * CM, SCH);
    }
}

// Round 18
// 306.988 us; speedup vs baseline: 1.2721x; 1.0340x over previous
//
#include <hip/hip_runtime.h>
#include <math.h>

#define S_DIM 512
#define R_DIM 384
#define CM 64
#define CZ 128
#define NH 8
#define CH 32
#define HC 256

typedef unsigned short u16;
typedef __attribute__((ext_vector_type(8))) __bf16 bf16x8;
typedef __attribute__((ext_vector_type(4))) float f32x4;

static __device__ __forceinline__ u16 f2bf(float f) {
    unsigned int u = __float_as_uint(f);
    unsigned int r = (u + 0x7fffu + ((u >> 16) & 1u)) >> 16;
    return (u16)r;
}
static __device__ __forceinline__ float bf2f(u16 h) {
    return __uint_as_float(((unsigned int)h) << 16);
}
static __device__ __forceinline__ void split2(float f, u16& hi, u16& lo) {
    hi = f2bf(f);
    lo = f2bf(f - bf2f(hi));
}
// LDS-only barrier: orders LDS ops across the workgroup WITHOUT draining
// outstanding global stores (vmcnt). Safe when no cross-wave global-memory
// hazard exists (kB: Vt/g stores are write-once, never read in-kernel).
static __device__ __forceinline__ void barrier_lds_only() {
    asm volatile("s_waitcnt lgkmcnt(0)" ::: "memory");
    __builtin_amdgcn_s_barrier();
    asm volatile("" ::: "memory");
}

// ---------------------------------------------------------------------------
// Prep: w_v, w_g -> bf16 hi/lo K-major (wvT[n][c] = w_v[c][n], n<256,c<64);
//       w_b -> wbT[n][c] = w_b[c][n] (n<16 padded, c<128), hi/lo.
// ---------------------------------------------------------------------------
__global__ __launch_bounds__(256) void kW_prep(
    const float* __restrict__ wv, const float* __restrict__ wg,
    const float* __restrict__ wb,
    u16* __restrict__ wvT_hi, u16* __restrict__ wvT_lo,
    u16* __restrict__ wgT_hi, u16* __restrict__ wgT_lo,
    u16* __restrict__ wbT_hi, u16* __restrict__ wbT_lo)
{
    const int idx = blockIdx.x * 256 + threadIdx.x;
    if (idx < 16384) {
        const int n = idx >> 6, c = idx & 63;
        split2(wv[c * HC + n], wvT_hi[idx], wvT_lo[idx]);
    } else if (idx < 32768) {
        const int r = idx - 16384;
        const int n = r >> 6, c = r & 63;
        split2(wg[c * HC + n], wgT_hi[r], wgT_lo[r]);
    } else if (idx < 34816) {
        const int r = idx - 32768;
        const int n = r >> 7, c = r & 127;
        split2(n < NH ? wb[c * NH + n] : 0.f, wbT_hi[r], wbT_lo[r]);
    }
}

// ---------------------------------------------------------------------------
// Kernel A1 (split-MFMA): bias[h][row] = LN(z[row,:]) @ w_b[:,h] + INF*(mask-1)
// ---------------------------------------------------------------------------
__global__ __launch_bounds__(256) void kA1_bias(
    const float* __restrict__ z, const float* __restrict__ z_mask,
    const float* __restrict__ ln_z_g, const float* __restrict__ ln_z_b,
    const u16* __restrict__ wbT_hi, const u16* __restrict__ wbT_lo,
    float* __restrict__ bias_ws)
{
    __shared__ __align__(16) u16 a_hi[128 * 136];
    __shared__ __align__(16) u16 a_lo[128 * 136];
    __shared__ __align__(16) u16 b_hi[16 * 136];
    __shared__ __align__(16) u16 b_lo[16 * 136];
    const int tid  = threadIdx.x;
    const int lane = tid & 63, w = tid >> 6;
    const int row0 = blockIdx.x * 128;

    {
        const int r = tid >> 1, half = tid & 1;
        const float* src = z + (size_t)(row0 + r) * CZ + half * 64;
        float x[64];
        float s1 = 0.f, s2 = 0.f;
        #pragma unroll
        for (int e = 0; e < 16; ++e) {
            float4 v4 = *reinterpret_cast<const float4*>(src + e * 4);
            x[e*4+0] = v4.x; x[e*4+1] = v4.y; x[e*4+2] = v4.z; x[e*4+3] = v4.w;
            s1 += v4.x + v4.y + v4.z + v4.w;
            s2 += v4.x*v4.x + v4.y*v4.y + v4.z*v4.z + v4.w*v4.w;
        }
        s1 += __shfl_xor(s1, 1);
        s2 += __shfl_xor(s2, 1);
        const float mu   = s1 * (1.f / CZ);
        const float var  = s2 * (1.f / CZ) - mu * mu;
        const float rstd = rsqrtf(var + 1e-5f);
        #pragma unroll
        for (int e = 0; e < 16; ++e) {
            float4 g4 = *reinterpret_cast<const float4*>(ln_z_g + half * 64 + e * 4);
            float4 b4 = *reinterpret_cast<const float4*>(ln_z_b + half * 64 + e * 4);
            const int c = half * 64 + e * 4;
            split2((x[e*4+0] - mu) * rstd * g4.x + b4.x,
                   a_hi[r * 136 + c + 0], a_lo[r * 136 + c + 0]);
            split2((x[e*4+1] - mu) * rstd * g4.y + b4.y,
                   a_hi[r * 136 + c + 1], a_lo[r * 136 + c + 1]);
            split2((x[e*4+2] - mu) * rstd * g4.z + b4.z,
                   a_hi[r * 136 + c + 2], a_lo[r * 136 + c + 2]);
            split2((x[e*4+3] - mu) * rstd * g4.w + b4.w,
                   a_hi[r * 136 + c + 3], a_lo[r * 136 + c + 3]);
        }
    }
    {
        const int row = tid >> 4, off = (tid & 15) * 8;
        *reinterpret_cast<uint4*>(&b_hi[row * 136 + off]) =
            *reinterpret_cast<const uint4*>(wbT_hi + row * 128 + off);
        *reinterpret_cast<uint4*>(&b_lo[row * 136 + off]) =
            *reinterpret_cast<const uint4*>(wbT_lo + row * 128 + off);
    }
    __syncthreads();

    const int wr = w * 32;
    f32x4 acc[2] = {};
    #pragma unroll
    for (int ks = 0; ks < 4; ++ks) {
        const int ko = ks * 32 + (lane >> 4) * 8;
        bf16x8 bh = *reinterpret_cast<const bf16x8*>(&b_hi[(lane & 15) * 136 + ko]);
        bf16x8 bl = *reinterpret_cast<const bf16x8*>(&b_lo[(lane & 15) * 136 + ko]);
        #pragma unroll
        for (int mm = 0; mm < 2; ++mm) {
            const int base = (wr + mm * 16 + (lane & 15)) * 136 + ko;
            bf16x8 ah = *reinterpret_cast<const bf16x8*>(&a_hi[base]);
            bf16x8 al = *reinterpret_cast<const bf16x8*>(&a_lo[base]);
            acc[mm] = __builtin_amdgcn_mfma_f32_16x16x32_bf16(ah, bh, acc[mm], 0, 0, 0);
            acc[mm] = __builtin_amdgcn_mfma_f32_16x16x32_bf16(al, bh, acc[mm], 0, 0, 0);
            acc[mm] = __builtin_amdgcn_mfma_f32_16x16x32_bf16(ah, bl, acc[mm], 0, 0, 0);
        }
    }

    __syncthreads();
    float* T = reinterpret_cast<float*>(a_hi);      // [8 h][132 rows] f32
    const int cl = lane & 15, r4 = (lane >> 4) * 4;
    #pragma unroll
    for (int mm = 0; mm < 2; ++mm) {
        if (cl < NH) {
            #pragma unroll
            for (int r = 0; r < 4; ++r)
                T[cl * 132 + wr + mm * 16 + r4 + r] = acc[mm][r];
        }
    }
    __syncthreads();
    {
        const int h = tid >> 5, q = (tid & 31) * 4;
        float4 v  = *reinterpret_cast<const float4*>(&T[h * 132 + q]);
        float4 mk = *reinterpret_cast<const float4*>(z_mask + row0 + q);
        v.x += 1e8f * (mk.x - 1.f);
        v.y += 1e8f * (mk.y - 1.f);
        v.z += 1e8f * (mk.z - 1.f);
        v.w += 1e8f * (mk.w - 1.f);
        *reinterpret_cast<float4*>(
            &bias_ws[(size_t)h * R_DIM * R_DIM + row0 + q]) = v;
    }
}

// ---------------------------------------------------------------------------
// Kernel A2: w_soft[h][i][j] = softmax_j(bias[h][i][j]) -> bf16
// ---------------------------------------------------------------------------
__global__ __launch_bounds__(256) void kA2_softmax(
    const float* __restrict__ bias_ws, u16* __restrict__ w_soft)
{
    const int tid = threadIdx.x, w = tid >> 6, lane = tid & 63;
    const int row = blockIdx.x * 4 + w;           // h*R + i
    const float* src = bias_ws + (size_t)row * R_DIM;
    float vals[6];
    float mx = -1e30f;
    #pragma unroll
    for (int u = 0; u < 6; ++u) {
        vals[u] = src[lane + u * 64];
        mx = fmaxf(mx, vals[u]);
    }
    #pragma unroll
    for (int msk = 32; msk >= 1; msk >>= 1) mx = fmaxf(mx, __shfl_xor(mx, msk));
    float sum = 0.f;
    #pragma unroll
    for (int u = 0; u < 6; ++u) { vals[u] = __expf(vals[u] - mx); sum += vals[u]; }
    #pragma unroll
    for (int msk = 32; msk >= 1; msk >>= 1) sum += __shfl_xor(sum, msk);
    const float inv = 1.0f / sum;
    u16* dst = w_soft + (size_t)row * R_DIM;
    #pragma unroll
    for (int u = 0; u < 6; ++u)
        dst[lane + u * 64] = f2bf(vals[u] * inv);
}

// ---------------------------------------------------------------------------
// Kernel B (split-MFMA, merged): stage+LN+split A ONCE (LDS), loop 4 weight
// tiles; B fragments direct from global. In-loop barriers are LDS-only
// (no vmcnt drain) so Vt/g global stores stay in flight across tiles.
//   Vt[h][jblk][n][jloc<128>]; g[kblk][si][kloc<128>]  (wave-contiguous)
// ---------------------------------------------------------------------------
__global__ __launch_bounds__(256) void kB_mfma(
    const float* __restrict__ m_chunk, const float* __restrict__ mask_chunk,
    const float* __restrict__ ln_g, const float* __restrict__ ln_b,
    const u16* __restrict__ wvT_hi, const u16* __restrict__ wvT_lo,
    const u16* __restrict__ wgT_hi, const u16* __restrict__ wgT_lo,
    u16* __restrict__ Vt, u16* __restrict__ gbuf, int SCH)
{
    __shared__ __align__(16) u16 a_hi[128 * 72];
    __shared__ __align__(16) u16 a_lo[128 * 72];
    __shared__ __align__(16) u16 Tbuf[128 * 136];
    const int tid  = threadIdx.x;
    const int si0  = blockIdx.x * 128;
    const int lane = tid & 63;
    const int w    = tid >> 6;
    const int wr   = (w >> 1) * 64, wc = (w & 1) * 64;

    {
        const int r = tid >> 1, half = tid & 1;
        const float* src = m_chunk + (size_t)(si0 + r) * CM + half * 32;
        float x[32];
        float s1 = 0.f, s2 = 0.f;
        #pragma unroll
        for (int e = 0; e < 8; ++e) {
            float4 v4 = *reinterpret_cast<const float4*>(src + e * 4);
            x[e*4+0] = v4.x; x[e*4+1] = v4.y; x[e*4+2] = v4.z; x[e*4+3] = v4.w;
            s1 += v4.x + v4.y + v4.z + v4.w;
            s2 += v4.x*v4.x + v4.y*v4.y + v4.z*v4.z + v4.w*v4.w;
        }
        s1 += __shfl_xor(s1, 1);
        s2 += __shfl_xor(s2, 1);
        const float mu   = s1 * (1.f / 64);
        const float var  = s2 * (1.f / 64) - mu * mu;
        const float rstd = rsqrtf(var + 1e-5f);
        u16 ph[32], pl[32];
        #pragma unroll
        for (int e = 0; e < 8; ++e) {
            #pragma unroll
            for (int q = 0; q < 4; ++q) {
                const int cl_ = e * 4 + q;
                const int c = half * 32 + cl_;
                const float v = (x[cl_] - mu) * rstd * ln_g[c] + ln_b[c];
                split2(v, ph[cl_], pl[cl_]);
            }
        }
        u16* dh = &a_hi[r * 72 + half * 32];
        u16* dl = &a_lo[r * 72 + half * 32];
        #pragma unroll
        for (int e = 0; e < 4; ++e) {
            *reinterpret_cast<uint4*>(dh + e * 8) =
                reinterpret_cast<const uint4*>(ph)[e];
            *reinterpret_cast<uint4*>(dl + e * 8) =
                reinterpret_cast<const uint4*>(pl)[e];
        }
    }
    __syncthreads();    // A visible to all waves; never rewritten after this

    #pragma unroll
    for (int t = 0; t < 4; ++t) {
        const int n0   = (t & 1) * 128;
        const bool isV = (t < 2);
        const u16* Wh = (isV ? wvT_hi : wgT_hi) + (size_t)n0 * 64;
        const u16* Wl = (isV ? wvT_lo : wgT_lo) + (size_t)n0 * 64;

        f32x4 acc[4][4] = {};
        #pragma unroll
        for (int ks = 0; ks < 2; ++ks) {
            const int ko = ks * 32 + (lane >> 4) * 8;
            bf16x8 ah[4], al[4], bh[4], bl[4];
            #pragma unroll
            for (int nn = 0; nn < 4; ++nn) {
                const size_t base = (size_t)(wc + nn * 16 + (lane & 15)) * 64 + ko;
                bh[nn] = *reinterpret_cast<const bf16x8*>(Wh + base);
                bl[nn] = *reinterpret_cast<const bf16x8*>(Wl + base);
            }
            #pragma unroll
            for (int mm = 0; mm < 4; ++mm) {
                const int abase = (wr + mm * 16 + (lane & 15)) * 72 + ko;
                ah[mm] = *reinterpret_cast<const bf16x8*>(&a_hi[abase]);
                al[mm] = *reinterpret_cast<const bf16x8*>(&a_lo[abase]);
            }
            #pragma unroll
            for (int mm = 0; mm < 4; ++mm)
                #pragma unroll
                for (int nn = 0; nn < 4; ++nn) {
                    acc[mm][nn] = __builtin_amdgcn_mfma_f32_16x16x32_bf16(
                        ah[mm], bh[nn], acc[mm][nn], 0, 0, 0);
                    acc[mm][nn] = __builtin_amdgcn_mfma_f32_16x16x32_bf16(
                        al[mm], bh[nn], acc[mm][nn], 0, 0, 0);
                    acc[mm][nn] = __builtin_amdgcn_mfma_f32_16x16x32_bf16(
                        ah[mm], bl[nn], acc[mm][nn], 0, 0, 0);
                }
        }
        // LDS-only: prior tile's Tbuf readers done; vmcnt stays outstanding
        barrier_lds_only();

        const int r4 = (lane >> 4) * 4, cl = lane & 15;
        if (isV) {
            #pragma unroll
            for (int mm = 0; mm < 4; ++mm) {
                const int rowb = wr + mm * 16 + r4;
                const float4 mk =
                    *reinterpret_cast<const float4*>(mask_chunk + si0 + rowb);
                #pragma unroll
                for (int nn = 0; nn < 4; ++nn) {
                    const int n = wc + nn * 16 + cl;
                    ushort4 pk;
                    pk.x = f2bf(acc[mm][nn][0] * mk.x);
                    pk.y = f2bf(acc[mm][nn][1] * mk.y);
                    pk.z = f2bf(acc[mm][nn][2] * mk.z);
                    pk.w = f2bf(acc[mm][nn][3] * mk.w);
                    *reinterpret_cast<ushort4*>(&Tbuf[n * 136 + rowb]) = pk;
                }
            }
            barrier_lds_only();
            const int sc   = si0 / R_DIM;
            const int jblk = (si0 % R_DIM) >> 7;
            const size_t Nn = (size_t)SCH * 32;
            #pragma unroll
            for (int e = 0; e < 8; ++e) {
                const int c = e * 256 + tid;
                const int n = c >> 4, part = c & 15;
                const int k = n0 + n;
                const int h = k >> 5, cc = k & 31;
                u16* dst = Vt + (((size_t)h * 3 + jblk) * Nn
                                 + (size_t)sc * 32 + cc) * 128 + part * 8;
                *reinterpret_cast<uint4*>(dst) =
                    *reinterpret_cast<const uint4*>(&Tbuf[n * 136 + part * 8]);
            }
        } else {
            #pragma unroll
            for (int mm = 0; mm < 4; ++mm) {
                const int rowb = wr + mm * 16 + r4;
                #pragma unroll
                for (int nn = 0; nn < 4; ++nn) {
                    const int n = wc + nn * 16 + cl;
                    #pragma unroll
                    for (int r = 0; r < 4; ++r)
                        Tbuf[(rowb + r) * 136 + n] =
                            f2bf(1.f / (1.f + __expf(-acc[mm][nn][r])));
                }
            }
            barrier_lds_only();
            const int kblk = n0 >> 7;
            const size_t SR = (size_t)SCH * R_DIM;
            #pragma unroll
            for (int e = 0; e < 8; ++e) {
                const int c = e * 256 + tid;
                const int row = c >> 4, part = c & 15;
                u16* dst = gbuf + ((size_t)kblk * SR + si0 + row) * 128 + part * 8;
                *reinterpret_cast<uint4*>(dst) =
                    *reinterpret_cast<const uint4*>(&Tbuf[row * 136 + part * 8]);
            }
        }
    }
}

// ---------------------------------------------------------------------------
// Kernel C: per-head MFMA GEMM  o_pre[i,n] = sum_j W_h[i,j] * V_h[j,n]
// Vt layout [h][jblk][n][jloc<128>]; writes o_pre bf16 [sc*R + i][h*32+c]
// ---------------------------------------------------------------------------
__global__ __launch_bounds__(256) void kC_mfma(
    const u16* __restrict__ Wsoft, const u16* __restrict__ Vt,
    u16* __restrict__ o_pre, int SCH)
{
    constexpr int LDSP = 40;
    __shared__ __align__(16) u16 lds_a[128 * LDSP];
    __shared__ __align__(16) u16 lds_b[128 * LDSP];
    const int N   = SCH * 32;
    const int n0  = blockIdx.x * 128;
    const int i0  = blockIdx.y * 128;
    const int h   = blockIdx.z;
    const int tid = threadIdx.x;
    const int lane = tid & 63;
    const int w    = tid >> 6;
    const int wr   = (w >> 1) * 64;
    const int wc   = (w & 1) * 64;

    const u16* Wp = Wsoft + (size_t)h * R_DIM * R_DIM;
    const u16* Vp = Vt    + (size_t)h * 3 * N * 128;

    f32x4 acc[4][4] = {};

    for (int k0 = 0; k0 < R_DIM; k0 += 32) {
        __syncthreads();
        const int jblk = k0 >> 7, jloc = k0 & 127;
        #pragma unroll
        for (int rep = 0; rep < 2; ++rep) {
            const int c = rep * 256 + tid;
            const int row = c >> 2, q = c & 3;
            uint4 va = *reinterpret_cast<const uint4*>(
                Wp + (size_t)(i0 + row) * R_DIM + k0 + q * 8);
            *reinterpret_cast<uint4*>(&lds_a[row * LDSP + q * 8]) = va;
            uint4 vb = *reinterpret_cast<const uint4*>(
                Vp + ((size_t)jblk * N + n0 + row) * 128 + jloc + q * 8);
            *reinterpret_cast<uint4*>(&lds_b[row * LDSP + q * 8]) = vb;
        }
        __syncthreads();

        bf16x8 afrag[4], bfrag[4];
        #pragma unroll
        for (int mm = 0; mm < 4; ++mm) {
            const int row = wr + mm * 16 + (lane & 15);
            afrag[mm] = *reinterpret_cast<const bf16x8*>(
                &lds_a[row * LDSP + (lane >> 4) * 8]);
        }
        #pragma unroll
        for (int nn = 0; nn < 4; ++nn) {
            const int row = wc + nn * 16 + (lane & 15);
            bfrag[nn] = *reinterpret_cast<const bf16x8*>(
                &lds_b[row * LDSP + (lane >> 4) * 8]);
        }
        #pragma unroll
        for (int mm = 0; mm < 4; ++mm)
            #pragma unroll
            for (int nn = 0; nn < 4; ++nn)
                acc[mm][nn] = __builtin_amdgcn_mfma_f32_16x16x32_bf16(
                    afrag[mm], bfrag[nn], acc[mm][nn], 0, 0, 0);
    }

    const int r4 = (lane >> 4) * 4;
    const int cl = lane & 15;
    #pragma unroll
    for (int mm = 0; mm < 4; ++mm) {
        #pragma unroll
        for (int nn = 0; nn < 4; ++nn) {
            const int i = i0 + wr + mm * 16 + r4;
            const int n = n0 + wc + nn * 16 + cl;
            const int sc = n >> 5, cc = n & 31;
            u16* dst = &o_pre[((size_t)sc * R_DIM + i) * HC + h * 32 + cc];
            #pragma unroll
            for (int r = 0; r < 4; ++r)
                dst[(size_t)r * HC] = f2bf(acc[mm][nn][r]);
        }
    }
}

// ---------------------------------------------------------------------------
// Kernel D: out[si, :] = (g[si,:] * o_pre[si,:]) @ w_o  (K=256, N=64)
// g layout [kblk][si][kloc<128>]; fp32 VALU GEMM (proven).
// ---------------------------------------------------------------------------
__global__ __launch_bounds__(256) void kD_out(
    const u16* __restrict__ gbuf, const u16* __restrict__ o_pre,
    const float* __restrict__ w_o, float* __restrict__ out_chunk, int SCH)
{
    __shared__ float A[128 * 65];
    __shared__ float Bt[64 * 64];
    const int si0 = blockIdx.x * 128;
    const int tid = threadIdx.x;
    const int tx  = tid & 15, ty = tid >> 4;
    const size_t SR = (size_t)SCH * R_DIM;
    float acc[8][4] = {};

    for (int k0 = 0; k0 < HC; k0 += 64) {
        { // A tile = g * o_pre (bf16 loads -> f32 product)
            const int r = tid >> 1, half = tid & 1;
            const size_t gb = ((size_t)(k0 >> 7) * SR + si0 + r) * 128
                              + (k0 & 127) + half * 32;
            const size_t ob = (size_t)(si0 + r) * HC + k0 + half * 32;
            float* dst = &A[r * 65 + half * 32];
            #pragma unroll
            for (int e = 0; e < 4; ++e) {
                uint4 gv = *reinterpret_cast<const uint4*>(gbuf + gb + e * 8);
                uint4 ov = *reinterpret_cast<const uint4*>(o_pre + ob + e * 8);
                const u16* ga = (const u16*)&gv;
                const u16* oa = (const u16*)&ov;
                #pragma unroll
                for (int q = 0; q < 8; ++q)
                    dst[e * 8 + q] = bf2f(ga[q]) * bf2f(oa[q]);
            }
        }
        { // w_o tile
            const int kk = tid >> 2, q = tid & 3;
            #pragma unroll
            for (int e = 0; e < 4; ++e) {
                float4 v4 = *reinterpret_cast<const float4*>(
                    w_o + (size_t)(k0 + kk) * CM + q * 16 + e * 4);
                *reinterpret_cast<float4*>(&Bt[kk * 64 + q * 16 + e * 4]) = v4;
            }
        }
        __syncthreads();
        #pragma unroll 8
        for (int kk = 0; kk < 64; ++kk) {
            float4 b = *reinterpret_cast<float4*>(&Bt[kk * 64 + tx * 4]);
            #pragma unroll
            for (int e = 0; e < 8; ++e) {
                float a = A[(ty * 8 + e) * 65 + kk];
                acc[e][0] += a * b.x; acc[e][1] += a * b.y;
                acc[e][2] += a * b.z; acc[e][3] += a * b.w;
            }
        }
        __syncthreads();
    }
    #pragma unroll
    for (int e = 0; e < 8; ++e) {
        *reinterpret_cast<float4*>(
            &out_chunk[(size_t)(si0 + ty * 8 + e) * CM + tx * 4]) =
            make_float4(acc[e][0], acc[e][1], acc[e][2], acc[e][3]);
    }
}

// ---------------------------------------------------------------------------
extern "C" void kernel_launch(void* const* d_in, const int* in_sizes, int n_in,
                              void* d_out, int out_size, void* d_ws, size_t ws_size,
                              hipStream_t stream)
{
    const float* m        = (const float*)d_in[0];
    const float* z        = (const float*)d_in[1];
    const float* msa_mask = (const float*)d_in[2];
    const float* z_mask   = (const float*)d_in[3];
    const float* ln_m_g   = (const float*)d_in[4];
    const float* ln_m_b   = (const float*)d_in[5];
    const float* w_v      = (const float*)d_in[6];
    const float* w_g      = (const float*)d_in[7];
    const float* ln_z_g   = (const float*)d_in[8];
    const float* ln_z_b   = (const float*)d_in[9];
    const float* w_b      = (const float*)d_in[10];
    const float* w_o      = (const float*)d_in[11];
    float* out = (float*)d_out;

    const size_t wsoft_bytes = (size_t)NH * R_DIM * R_DIM * 2;       // bf16
    const size_t bias_bytes  = (size_t)NH * R_DIM * R_DIM * 4;       // f32
    const size_t wts_bytes   = 4 * 16384 * 2 + 2 * 2048 * 2;
    // per s-row: Vt bf16 + g bf16 + o_pre bf16
    const size_t per_sch = (size_t)R_DIM * HC * (2 + 2 + 2);
    int SCH = 256;
    while (SCH > 4 &&
           wsoft_bytes + bias_bytes + wts_bytes + (size_t)SCH * per_sch > ws_size)
        SCH >>= 1;

    char* p = (char*)d_ws;
    u16* w_soft   = (u16*)p; p += wsoft_bytes;
    float* biasws = (float*)p; p += bias_bytes;
    u16* wvT_hi   = (u16*)p; p += 16384 * 2;
    u16* wvT_lo   = (u16*)p; p += 16384 * 2;
    u16* wgT_hi   = (u16*)p; p += 16384 * 2;
    u16* wgT_lo   = (u16*)p; p += 16384 * 2;
    u16* wbT_hi   = (u16*)p; p += 2048 * 2;
    u16* wbT_lo   = (u16*)p; p += 2048 * 2;
    u16* Vt       = (u16*)p; p += (size_t)SCH * 32 * NH * R_DIM * 2;
    u16* gbuf     = (u16*)p; p += (size_t)SCH * R_DIM * HC * 2;
    u16* obuf     = (u16*)p;

    kW_prep<<<136, 256, 0, stream>>>(w_v, w_g, w_b, wvT_hi, wvT_lo,
                                     wgT_hi, wgT_lo, wbT_hi, wbT_lo);
    kA1_bias<<<R_DIM * R_DIM / 128, 256, 0, stream>>>(
        z, z_mask, ln_z_g, ln_z_b, wbT_hi, wbT_lo, biasws);
    kA2_softmax<<<NH * R_DIM / 4, 256, 0, stream>>>(biasws, w_soft);

    for (int s0 = 0; s0 < S_DIM; s0 += SCH) {
        kB_mfma<<<dim3(SCH * 3), 256, 0, stream>>>(
            m + (size_t)s0 * R_DIM * CM, msa_mask + (size_t)s0 * R_DIM,
            ln_m_g, ln_m_b, wvT_hi, wvT_lo, wgT_hi, wgT_lo, Vt, gbuf, SCH);
        kC_mfma<<<dim3(SCH / 4, 3, NH), 256, 0, stream>>>(w_soft, Vt, obuf, SCH);
        kD_out<<<dim3(SCH * 3), 256, 0, stream>>>(gbuf, obuf, w_o,
                                                  out + (size_t)s0 * R_DIM * CM, SCH);
    }
}